// Round 1
// baseline (3388.457 us; speedup 1.0000x reference)
//
#include <hip/hip_runtime.h>
#include <math.h>

#define BATCH   4
#define SEQ     2048
#define DMODEL  1024
#define NH      16
#define DHEAD   64
#define OUT_ELEMS   ((size_t)BATCH * SEQ * DMODEL)      // 8388608
#define HEAD_STRIDE ((size_t)SEQ * DHEAD)               // 131072

// ---------------------------------------------------------------------------
// Projection GEMM: Y = X(M,1024) @ W(1024,1024) + b
// 128x128 tile, BK=16, 256 threads, 8x8 micro-tile (split 4+4 rows/cols).
// split_heads=1: Y scattered to (B,H,S,64) layout; else row-major (M,1024).
// ---------------------------------------------------------------------------
__global__ __launch_bounds__(256) void proj_gemm_kernel(
    const float* __restrict__ A, const float* __restrict__ W,
    const float* __restrict__ bias, float* __restrict__ out, int split_heads)
{
    __shared__ __align__(16) float As[16][132];  // [k][m], pad keeps 16B align + 2-way banks
    __shared__ __align__(16) float Bs[16][128];  // [k][n]
    const int tid = threadIdx.x;
    const int tx = tid & 15;
    const int ty = tid >> 4;
    const int m0 = blockIdx.y * 128;
    const int n0 = blockIdx.x * 128;

    float acc[8][8];
#pragma unroll
    for (int i = 0; i < 8; ++i)
#pragma unroll
        for (int j = 0; j < 8; ++j) acc[i][j] = 0.f;

    const int am = tid >> 1;           // 0..127 (A tile row)
    const int ak = (tid & 1) * 8;      // 0 or 8 (A tile col base)
    const int bk = tid >> 4;           // 0..15  (B tile row)
    const int bn = (tid & 15) * 8;     // B tile col base

    for (int k0 = 0; k0 < DMODEL; k0 += 16) {
        float4 a0 = *(const float4*)(A + (size_t)(m0 + am) * DMODEL + k0 + ak);
        float4 a1 = *(const float4*)(A + (size_t)(m0 + am) * DMODEL + k0 + ak + 4);
        float4 b0 = *(const float4*)(W + (size_t)(k0 + bk) * DMODEL + n0 + bn);
        float4 b1 = *(const float4*)(W + (size_t)(k0 + bk) * DMODEL + n0 + bn + 4);
        // transpose A into [k][m]
        As[ak + 0][am] = a0.x; As[ak + 1][am] = a0.y;
        As[ak + 2][am] = a0.z; As[ak + 3][am] = a0.w;
        As[ak + 4][am] = a1.x; As[ak + 5][am] = a1.y;
        As[ak + 6][am] = a1.z; As[ak + 7][am] = a1.w;
        *(float4*)&Bs[bk][bn]     = b0;
        *(float4*)&Bs[bk][bn + 4] = b1;
        __syncthreads();
#pragma unroll
        for (int k = 0; k < 16; ++k) {
            float4 x0 = *(const float4*)&As[k][ty * 4];
            float4 x1 = *(const float4*)&As[k][64 + ty * 4];
            float4 y0 = *(const float4*)&Bs[k][tx * 4];
            float4 y1 = *(const float4*)&Bs[k][64 + tx * 4];
            float a[8] = {x0.x, x0.y, x0.z, x0.w, x1.x, x1.y, x1.z, x1.w};
            float b[8] = {y0.x, y0.y, y0.z, y0.w, y1.x, y1.y, y1.z, y1.w};
#pragma unroll
            for (int i = 0; i < 8; ++i)
#pragma unroll
                for (int j = 0; j < 8; ++j)
                    acc[i][j] = fmaf(a[i], b[j], acc[i][j]);
        }
        __syncthreads();
    }

#pragma unroll
    for (int ih = 0; ih < 2; ++ih) {
#pragma unroll
        for (int i = 0; i < 4; ++i) {
            const int m  = m0 + ih * 64 + ty * 4 + i;
            const int bb = m >> 11;       // batch
            const int s  = m & 2047;      // seq pos
#pragma unroll
            for (int jh = 0; jh < 2; ++jh) {
                const int n = n0 + jh * 64 + tx * 4;
                float4 r;
                r.x = acc[ih * 4 + i][jh * 4 + 0] + bias[n + 0];
                r.y = acc[ih * 4 + i][jh * 4 + 1] + bias[n + 1];
                r.z = acc[ih * 4 + i][jh * 4 + 2] + bias[n + 2];
                r.w = acc[ih * 4 + i][jh * 4 + 3] + bias[n + 3];
                if (split_heads) {
                    const int h = n >> 6, d = n & 63;
                    *(float4*)(out + (((size_t)(bb * NH + h) * SEQ + s) * DHEAD + d)) = r;
                } else {
                    *(float4*)(out + (size_t)m * DMODEL + n) = r;
                }
            }
        }
    }
}

// ---------------------------------------------------------------------------
// Raw scaled logits: L[s,t] = 0.125 * sum_d Q[s,d]*K[t,d]   (per b,h)
// 64x64 tile, K=64 single shot, 4x4 micro. Written into attn region of d_out.
// ---------------------------------------------------------------------------
__global__ __launch_bounds__(256) void qk_logits_kernel(
    const float* __restrict__ Qh, const float* __restrict__ Kh,
    float* __restrict__ logits)
{
    __shared__ __align__(16) float Qs[64][68];  // [d][s]  (transposed)
    __shared__ __align__(16) float Ks[64][68];  // [d][t]  (transposed)
    const int tid = threadIdx.x;
    const int tx = tid & 15, ty = tid >> 4;
    const int t0 = blockIdx.x * 64;
    const int s0 = blockIdx.y * 64;
    const int z  = blockIdx.z;                  // b*16 + h
    const float* Qb = Qh + (size_t)z * HEAD_STRIDE;
    const float* Kb = Kh + (size_t)z * HEAD_STRIDE;

    const int r = tid >> 2;       // 0..63 tile row
    const int c = tid & 3;        // 0..3
#pragma unroll
    for (int qq = 0; qq < 4; ++qq) {
        const int col = qq * 16 + c * 4;     // contiguous 64B per row per qq
        float4 qv = *(const float4*)(Qb + (size_t)(s0 + r) * DHEAD + col);
        float4 kv = *(const float4*)(Kb + (size_t)(t0 + r) * DHEAD + col);
        Qs[col + 0][r] = qv.x; Qs[col + 1][r] = qv.y;
        Qs[col + 2][r] = qv.z; Qs[col + 3][r] = qv.w;
        Ks[col + 0][r] = kv.x; Ks[col + 1][r] = kv.y;
        Ks[col + 2][r] = kv.z; Ks[col + 3][r] = kv.w;
    }
    __syncthreads();

    float acc[4][4];
#pragma unroll
    for (int i = 0; i < 4; ++i)
#pragma unroll
        for (int j = 0; j < 4; ++j) acc[i][j] = 0.f;

#pragma unroll 16
    for (int d = 0; d < 64; ++d) {
        float4 qv = *(const float4*)&Qs[d][ty * 4];
        float4 kv = *(const float4*)&Ks[d][tx * 4];
        float a[4] = {qv.x, qv.y, qv.z, qv.w};
        float b[4] = {kv.x, kv.y, kv.z, kv.w};
#pragma unroll
        for (int i = 0; i < 4; ++i)
#pragma unroll
            for (int j = 0; j < 4; ++j)
                acc[i][j] = fmaf(a[i], b[j], acc[i][j]);
    }

    float* Lb = logits + (size_t)z * SEQ * SEQ;
#pragma unroll
    for (int i = 0; i < 4; ++i) {
        float4 rr;
        rr.x = acc[i][0] * 0.125f; rr.y = acc[i][1] * 0.125f;
        rr.z = acc[i][2] * 0.125f; rr.w = acc[i][3] * 0.125f;
        *(float4*)(Lb + (size_t)(s0 + ty * 4 + i) * SEQ + t0 + tx * 4) = rr;
    }
}

// ---------------------------------------------------------------------------
// In-place masked softmax over 2048-wide rows of attn.
// grid = (H, SEQ, B) with h fastest so 16 consecutive blocks share a mask row.
// ---------------------------------------------------------------------------
__global__ __launch_bounds__(256) void softmax_kernel(
    float* __restrict__ attn, const float* __restrict__ mask)
{
    const int h = blockIdx.x, s = blockIdx.y, b = blockIdx.z;
    const int tid = threadIdx.x;
    float* row = attn + ((size_t)(b * NH + h) * SEQ + s) * SEQ;
    const float* mrow = mask + ((size_t)b * SEQ + s) * SEQ;

    float4 v0 = *(const float4*)(row + tid * 4);
    float4 v1 = *(const float4*)(row + 1024 + tid * 4);
    float4 m0 = *(const float4*)(mrow + tid * 4);
    float4 m1 = *(const float4*)(mrow + 1024 + tid * 4);
    float x[8];
    x[0] = v0.x - 1e9f * m0.x; x[1] = v0.y - 1e9f * m0.y;
    x[2] = v0.z - 1e9f * m0.z; x[3] = v0.w - 1e9f * m0.w;
    x[4] = v1.x - 1e9f * m1.x; x[5] = v1.y - 1e9f * m1.y;
    x[6] = v1.z - 1e9f * m1.z; x[7] = v1.w - 1e9f * m1.w;

    float lmax = x[0];
#pragma unroll
    for (int i = 1; i < 8; ++i) lmax = fmaxf(lmax, x[i]);
#pragma unroll
    for (int off = 32; off; off >>= 1)
        lmax = fmaxf(lmax, __shfl_xor(lmax, off, 64));

    __shared__ float red[8];
    const int wv = tid >> 6, ln = tid & 63;
    if (ln == 0) red[wv] = lmax;
    __syncthreads();
    const float M = fmaxf(fmaxf(red[0], red[1]), fmaxf(red[2], red[3]));

    float e[8];
    float lsum = 0.f;
#pragma unroll
    for (int i = 0; i < 8; ++i) { e[i] = __expf(x[i] - M); lsum += e[i]; }
#pragma unroll
    for (int off = 32; off; off >>= 1)
        lsum += __shfl_xor(lsum, off, 64);
    if (ln == 0) red[4 + wv] = lsum;
    __syncthreads();
    const float S = red[4] + red[5] + red[6] + red[7];
    const float inv = 1.0f / S;

    v0.x = e[0] * inv; v0.y = e[1] * inv; v0.z = e[2] * inv; v0.w = e[3] * inv;
    v1.x = e[4] * inv; v1.y = e[5] * inv; v1.z = e[6] * inv; v1.w = e[7] * inv;
    *(float4*)(row + tid * 4) = v0;
    *(float4*)(row + 1024 + tid * 4) = v1;
}

// ---------------------------------------------------------------------------
// ctx = attn @ V per head: (2048x2048)@(2048x64). 64(s) x 64(d) tile per
// block, K-loop over t in 64-chunks. ctx written in (B,S,H,D) layout.
// ---------------------------------------------------------------------------
__global__ __launch_bounds__(256) void attn_v_kernel(
    const float* __restrict__ attn, const float* __restrict__ Vh,
    float* __restrict__ ctx)
{
    __shared__ __align__(16) float As_T[64][68];  // [t][s] (transposed attn tile)
    __shared__ __align__(16) float Vs[64][68];    // [t][d]
    const int tid = threadIdx.x;
    const int tx = tid & 15, ty = tid >> 4;
    const int s0 = blockIdx.x * 64;
    const int z  = blockIdx.y;                    // b*16 + h
    const int b  = z >> 4, h = z & 15;
    const float* Ab = attn + (size_t)z * SEQ * SEQ;
    const float* Vb = Vh + (size_t)z * HEAD_STRIDE;
    const int r = tid >> 2, c = tid & 3;

    float acc[4][4];
#pragma unroll
    for (int i = 0; i < 4; ++i)
#pragma unroll
        for (int j = 0; j < 4; ++j) acc[i][j] = 0.f;

    for (int t0 = 0; t0 < SEQ; t0 += 64) {
#pragma unroll
        for (int qq = 0; qq < 4; ++qq) {
            const int col = qq * 16 + c * 4;
            float4 av = *(const float4*)(Ab + (size_t)(s0 + r) * SEQ + t0 + col);
            As_T[col + 0][r] = av.x; As_T[col + 1][r] = av.y;
            As_T[col + 2][r] = av.z; As_T[col + 3][r] = av.w;
            float4 vv = *(const float4*)(Vb + (size_t)(t0 + r) * DHEAD + col);
            *(float4*)&Vs[r][col] = vv;
        }
        __syncthreads();
#pragma unroll 16
        for (int t = 0; t < 64; ++t) {
            float4 av = *(const float4*)&As_T[t][ty * 4];
            float4 vv = *(const float4*)&Vs[t][tx * 4];
            float a[4] = {av.x, av.y, av.z, av.w};
            float v[4] = {vv.x, vv.y, vv.z, vv.w};
#pragma unroll
            for (int i = 0; i < 4; ++i)
#pragma unroll
                for (int j = 0; j < 4; ++j)
                    acc[i][j] = fmaf(a[i], v[j], acc[i][j]);
        }
        __syncthreads();
    }

#pragma unroll
    for (int i = 0; i < 4; ++i) {
        float4 rr;
        rr.x = acc[i][0]; rr.y = acc[i][1]; rr.z = acc[i][2]; rr.w = acc[i][3];
        *(float4*)(ctx + ((size_t)b * SEQ + s0 + ty * 4 + i) * DMODEL + h * DHEAD + tx * 4) = rr;
    }
}

// ---------------------------------------------------------------------------
extern "C" void kernel_launch(void* const* d_in, const int* in_sizes, int n_in,
                              void* d_out, int out_size, void* d_ws, size_t ws_size,
                              hipStream_t stream)
{
    const float* q    = (const float*)d_in[0];
    const float* k    = (const float*)d_in[1];
    const float* v    = (const float*)d_in[2];
    const float* mask = (const float*)d_in[3];
    const float* Wq   = (const float*)d_in[4];
    const float* bq   = (const float*)d_in[5];
    const float* Wk   = (const float*)d_in[6];
    const float* bk   = (const float*)d_in[7];
    const float* Wv   = (const float*)d_in[8];
    const float* bv   = (const float*)d_in[9];
    const float* Wo   = (const float*)d_in[10];
    const float* bo   = (const float*)d_in[11];

    float* out  = (float*)d_out;
    float* attn = out + OUT_ELEMS;                      // 268,435,456 floats

    float* ws  = (float*)d_ws;
    const size_t HBUF = (size_t)BATCH * NH * SEQ * DHEAD;  // 8,388,608 floats
    float* Qh  = ws;
    float* Kh  = ws + HBUF;
    float* Vh  = ws + 2 * HBUF;
    float* ctx = ws;          // reuse Qh region: Qh dead after qk_logits

    dim3 blk(256);
    // Q/K/V projections -> head-split layout in workspace
    proj_gemm_kernel<<<dim3(8, 64), blk, 0, stream>>>(q, Wq, bq, Qh, 1);
    proj_gemm_kernel<<<dim3(8, 64), blk, 0, stream>>>(k, Wk, bk, Kh, 1);
    proj_gemm_kernel<<<dim3(8, 64), blk, 0, stream>>>(v, Wv, bv, Vh, 1);
    // raw scaled logits into attn region of d_out
    qk_logits_kernel<<<dim3(32, 32, 64), blk, 0, stream>>>(Qh, Kh, attn);
    // in-place masked softmax (h fastest for mask-row L2 reuse)
    softmax_kernel<<<dim3(NH, SEQ, BATCH), blk, 0, stream>>>(attn, mask);
    // ctx = attn @ V   (ctx overwrites Qh region, safe: Qh consumed)
    attn_v_kernel<<<dim3(32, 64), blk, 0, stream>>>(attn, Vh, ctx);
    // out = ctx @ Wo + bo
    proj_gemm_kernel<<<dim3(8, 64), blk, 0, stream>>>(ctx, Wo, bo, out, 0);
}